// Round 3
// baseline (1051.840 us; speedup 1.0000x reference)
//
#include <hip/hip_runtime.h>
#include <cstdint>
#include <cstddef>

// Problem constants (fixed by the reference)
#define TT 1024          // seq len
#define BB 4             // batch
#define DDIM 1024        // d_model
#define HH 16            // heads
#define HKK 64           // head dim
#define MR (BB*TT)       // 4096 token rows

typedef __attribute__((__ext_vector_type__(8))) __bf16 bf16x8;
typedef __attribute__((__ext_vector_type__(4))) float f32x4;
typedef __attribute__((__ext_vector_type__(4))) unsigned short us4;
typedef __attribute__((__ext_vector_type__(4))) unsigned int ui4;

__device__ __forceinline__ unsigned short f2bf(float f) {
  unsigned int u = __builtin_bit_cast(unsigned int, f);
  u += 0x7fffu + ((u >> 16) & 1u);   // round-to-nearest-even
  return (unsigned short)(u >> 16);
}

// Direct global->LDS DMA, 16B per lane. LDS dest must be WAVE-UNIFORM base;
// HW writes lane l at base + l*16 (m104/m108). Casts go through uintptr_t
// (CK pattern) so they are legal integer->pointer reinterprets.
__device__ __forceinline__ void gload_lds16(const void* g, void* lds) {
  __builtin_amdgcn_global_load_lds(
      reinterpret_cast<const __attribute__((address_space(1))) unsigned int*>(
          reinterpret_cast<uintptr_t>(g)),
      reinterpret_cast<__attribute__((address_space(3))) unsigned int*>(
          reinterpret_cast<uintptr_t>(lds)),
      16, 0, 0);
}

// ---------------------------------------------------------------------------
// k0a: cast the 8 weight matrices (fp32 [1024][1024], row = out e, col = in d)
// to bf16 into Wb[8][1024*1024]
// ---------------------------------------------------------------------------
__global__ __launch_bounds__(256) void cast_weights(
    const float* __restrict__ W0, const float* __restrict__ W1,
    const float* __restrict__ W2, const float* __restrict__ W3,
    const float* __restrict__ W4, const float* __restrict__ W5,
    const float* __restrict__ W6, const float* __restrict__ W7,
    unsigned short* __restrict__ Wb)
{
  int idx = blockIdx.x * 256 + threadIdx.x;      // one float4 per thread
  int mid = idx >> 18;                            // 262144 float4s per matrix
  int off = idx & 262143;
  const float* W;
  switch (mid) {
    case 0: W = W0; break; case 1: W = W1; break;
    case 2: W = W2; break; case 3: W = W3; break;
    case 4: W = W4; break; case 5: W = W5; break;
    case 6: W = W6; break; default: W = W7; break;
  }
  float4 v = ((const float4*)W)[off];
  us4 o;
  o.x = f2bf(v.x); o.y = f2bf(v.y); o.z = f2bf(v.z); o.w = f2bf(v.w);
  *(us4*)&Wb[(size_t)mid * (1024u*1024u) + (size_t)off * 4] = o;
}

// ---------------------------------------------------------------------------
// k0b: build the 7 token-shift-mixed inputs in bf16:
//   xm[c][bt][d] = x[bt][d] + (prev[bt][d] - x[bt][d]) * mix_c[d]
// prev = x shifted by one token within each batch row (zero at t=0)
// ---------------------------------------------------------------------------
__global__ __launch_bounds__(256) void prep_mix(
    const float* __restrict__ x,
    const float* __restrict__ m0, const float* __restrict__ m1,
    const float* __restrict__ m2, const float* __restrict__ m3,
    const float* __restrict__ m4, const float* __restrict__ m5,
    const float* __restrict__ m6,
    unsigned short* __restrict__ xm)
{
  int idx = blockIdx.x * 256 + threadIdx.x;   // one float4 per thread; 1048576 total
  int dq  = idx & 255;                        // float4 index within the row
  int bt  = idx >> 8;
  int t   = bt & (TT - 1);
  const float4* x4 = (const float4*)x;
  float4 xv = x4[idx];
  float4 pv = make_float4(0.f, 0.f, 0.f, 0.f);
  if (t != 0) pv = x4[idx - 256];
  float4 dx = make_float4(pv.x - xv.x, pv.y - xv.y, pv.z - xv.z, pv.w - xv.w);
  const float* mixes[7] = {m0, m1, m2, m3, m4, m5, m6};
  const size_t MD = (size_t)MR * DDIM;
#pragma unroll
  for (int c = 0; c < 7; ++c) {
    float4 mc = ((const float4*)mixes[c])[dq];
    us4 o;
    o.x = f2bf(xv.x + dx.x * mc.x);
    o.y = f2bf(xv.y + dx.y * mc.y);
    o.z = f2bf(xv.z + dx.z * mc.z);
    o.w = f2bf(xv.w + dx.w * mc.w);
    *(us4*)&xm[c * MD + (size_t)idx * 4] = o;
  }
}

// ---------------------------------------------------------------------------
// GEMM: C[m][n] = sum_k A[m][k] * B[n][k]   (A,B bf16 row-major-K, C fp32)
// 128x128 tile, BK=32, 256 threads (4 waves 2x2), mfma_f32_16x16x32_bf16.
// Staging: global_load_lds width=16 (m97 structure, 2 barriers per K-step).
// LDS layout is linear in tid (byte off = tid*16) so the wave-uniform-base
// + lane*16 HW write pattern lands each lane exactly where ds_reads expect.
// Fused epilogue modes: 0 none | 1 sigmoid(-y) (exp(w) decay) | 2 tanh |
//                       3 sigmoid | 4 per-head l2norm (head==wave 64-col span) |
//                       5 +bias[col]
// mode_override<0: per-z table {r,w,k,v,a,b,g} = {0,1,2,0,4,4,3}
// ---------------------------------------------------------------------------
__global__ __launch_bounds__(256) void gemm_bt(
    const unsigned short* __restrict__ Aall,
    const unsigned short* __restrict__ Ball,
    float* __restrict__ Call,
    int M, int N, int K,
    size_t strideAz, size_t strideBz, size_t strideCz,
    int mode_override,
    const float* __restrict__ bias)
{
  (void)M;
  const int z = blockIdx.z;
  const unsigned short* A = Aall + (size_t)z * strideAz;
  const unsigned short* B = Ball + (size_t)z * strideBz;
  float* C = Call + (size_t)z * strideCz;
  int mode = mode_override;
  if (mode < 0) mode = (z == 1) ? 1 : (z == 2) ? 2 : (z == 4 || z == 5) ? 4 : (z == 6) ? 3 : 0;

  __shared__ unsigned short As[128 * 32];
  __shared__ unsigned short Bs[128 * 32];

  const int tid  = threadIdx.x;
  const int lane = tid & 63;
  const int wv   = tid >> 6;
  const int wr   = wv >> 1, wc = wv & 1;
  const int lr   = lane & 15, lh = lane >> 4;
  const int m0   = blockIdx.y * 128;
  const int n0   = blockIdx.x * 128;

  // staging geometry: thread tid sources 16B at row sr=(tid>>2), col 8*(tid&3);
  // its LDS slot is byte offset tid*16 == (wave base wv*1024) + lane*16
  const int sr = tid >> 2;
  const int sc = (tid & 3) * 8;
  char* asb = (char*)As + wv * 1024;   // wave-uniform LDS bases
  char* bsb = (char*)Bs + wv * 1024;

  f32x4 acc[4][4];
#pragma unroll
  for (int m = 0; m < 4; ++m)
#pragma unroll
    for (int n = 0; n < 4; ++n)
      acc[m][n] = (f32x4){0.f, 0.f, 0.f, 0.f};

  const unsigned short* a0p = A + (size_t)(m0 + sr) * K + sc;
  const unsigned short* a1p = A + (size_t)(m0 + 64 + sr) * K + sc;
  const unsigned short* b0p = B + (size_t)(n0 + sr) * K + sc;
  const unsigned short* b1p = B + (size_t)(n0 + 64 + sr) * K + sc;

  for (int k0 = 0; k0 < K; k0 += 32) {
    __syncthreads();                 // previous compute done reading LDS
    gload_lds16(a0p + k0, asb);
    gload_lds16(a1p + k0, asb + 4096);   // half1 starts at 64*32*2B
    gload_lds16(b0p + k0, bsb);
    gload_lds16(b1p + k0, bsb + 4096);
    __syncthreads();                 // drains vmcnt(0): tile ready
    bf16x8 af[4], bfr[4];
#pragma unroll
    for (int m = 0; m < 4; ++m)
      af[m] = *(const bf16x8*)&As[(wr * 64 + m * 16 + lr) * 32 + lh * 8];
#pragma unroll
    for (int n = 0; n < 4; ++n)
      bfr[n] = *(const bf16x8*)&Bs[(wc * 64 + n * 16 + lr) * 32 + lh * 8];
#pragma unroll
    for (int m = 0; m < 4; ++m)
#pragma unroll
      for (int n = 0; n < 4; ++n)
        acc[m][n] = __builtin_amdgcn_mfma_f32_16x16x32_bf16(af[m], bfr[n], acc[m][n], 0, 0, 0);
  }

  if (mode == 4) {
    // per-head l2norm: wave's 64-col span is exactly one head (n0,wc are 64-aligned)
#pragma unroll
    for (int m = 0; m < 4; ++m) {
#pragma unroll
      for (int r = 0; r < 4; ++r) {
        float ss = 0.f;
#pragma unroll
        for (int n = 0; n < 4; ++n) { float v = acc[m][n][r]; ss += v * v; }
        ss += __shfl_xor(ss, 1); ss += __shfl_xor(ss, 2);
        ss += __shfl_xor(ss, 4); ss += __shfl_xor(ss, 8);
        float scale = 1.f / fmaxf(sqrtf(ss), 1e-6f);
#pragma unroll
        for (int n = 0; n < 4; ++n) acc[m][n][r] *= scale;
      }
    }
  }

#pragma unroll
  for (int m = 0; m < 4; ++m) {
#pragma unroll
    for (int n = 0; n < 4; ++n) {
      int col = n0 + wc * 64 + n * 16 + lr;
#pragma unroll
      for (int r = 0; r < 4; ++r) {
        int row = m0 + wr * 64 + m * 16 + lh * 4 + r;
        float v = acc[m][n][r];
        if (mode == 1)      v = 1.f / (1.f + __expf(v));    // exp(w)=sigmoid(-y)
        else if (mode == 2) v = tanhf(v);
        else if (mode == 3) v = 1.f / (1.f + __expf(-v));
        else if (mode == 5) v += bias[col];
        C[(size_t)row * N + col] = v;
      }
    }
  }
}

// ---------------------------------------------------------------------------
// RWKV7 scan: 64 blocks (one per (b,h)), 256 threads (4 waves).
// lane i = v-row of the 64x64 state; wave wv owns j in [16*wv, 16*wv+16).
// Y layout: [7][4096][1024] fp32 = r, decay(=exp(w)), k, v, a, b, g
// ---------------------------------------------------------------------------
__global__ __launch_bounds__(256) void rwkv_scan(
    const float* __restrict__ Y, float* __restrict__ og)
{
  const int bh = blockIdx.x;
  const int b = bh >> 4, h = bh & 15;
  const int tid = threadIdx.x;
  const int i  = tid & 63;
  const int wv = tid >> 6;
  const int j0 = wv * 16;

  __shared__ float vecs[6 * 64];     // 0:r 1:decay 2:k 3:v 4:a 5:b
  __shared__ float sa_part[4 * 64];
  __shared__ float o_part[4 * 64];

  const size_t MD = (size_t)MR * DDIM;
  const size_t rowbase = (size_t)(b * TT) * DDIM + h * HKK;

  // staging assignment
  const float* P0; const float* P1 = nullptr; int s0, s1 = -1;
  if (wv == 0)      { P0 = Y + 0 * MD; s0 = 0; P1 = Y + 1 * MD; s1 = 1; }
  else if (wv == 1) { P0 = Y + 2 * MD; s0 = 2; P1 = Y + 3 * MD; s1 = 3; }
  else if (wv == 2) { P0 = Y + 4 * MD; s0 = 4; }
  else              { P0 = Y + 5 * MD; s0 = 5; }

  float S[16];
#pragma unroll
  for (int jj = 0; jj < 16; ++jj) S[jj] = 0.f;

  float pf0 = P0[rowbase + i];
  float pf1 = (s1 >= 0) ? P1[rowbase + i] : 0.f;

  for (int t = 0; t < TT; ++t) {
    vecs[s0 * 64 + i] = pf0;
    if (s1 >= 0) vecs[s1 * 64 + i] = pf1;
    __syncthreads();                                     // #1: vecs ready
    if (t + 1 < TT) {                                    // prefetch next step
      size_t nb = rowbase + (size_t)(t + 1) * DDIM + i;
      pf0 = P0[nb];
      if (s1 >= 0) pf1 = P1[nb];
    }
    // sa partial from OLD state
    float p;
    {
      const float4* a4 = (const float4*)&vecs[4 * 64 + j0];
      float4 A0 = a4[0], A1 = a4[1], A2 = a4[2], A3 = a4[3];
      p  = S[0]*A0.x + S[1]*A0.y + S[2]*A0.z + S[3]*A0.w;
      p += S[4]*A1.x + S[5]*A1.y + S[6]*A1.z + S[7]*A1.w;
      p += S[8]*A2.x + S[9]*A2.y + S[10]*A2.z + S[11]*A2.w;
      p += S[12]*A3.x + S[13]*A3.y + S[14]*A3.z + S[15]*A3.w;
    }
    sa_part[wv * 64 + i] = p;
    __syncthreads();                                     // #2: sa parts ready
    float sa = sa_part[i] + sa_part[64 + i] + sa_part[128 + i] + sa_part[192 + i];
    float vi = vecs[3 * 64 + i];
    const float4* e4  = (const float4*)&vecs[1 * 64 + j0];
    const float4* k4  = (const float4*)&vecs[2 * 64 + j0];
    const float4* b4p = (const float4*)&vecs[5 * 64 + j0];
    const float4* r4  = (const float4*)&vecs[0 * 64 + j0];
    float q = 0.f;
#pragma unroll
    for (int u = 0; u < 4; ++u) {
      float4 ew = e4[u], kv = k4[u], bv = b4p[u], rv = r4[u];
      float t0 = S[u*4+0]*ew.x + sa*bv.x + vi*kv.x; S[u*4+0] = t0; q += t0*rv.x;
      float t1 = S[u*4+1]*ew.y + sa*bv.y + vi*kv.y; S[u*4+1] = t1; q += t1*rv.y;
      float t2 = S[u*4+2]*ew.z + sa*bv.z + vi*kv.z; S[u*4+2] = t2; q += t2*rv.z;
      float t3 = S[u*4+3]*ew.w + sa*bv.w + vi*kv.w; S[u*4+3] = t3; q += t3*rv.w;
    }
    o_part[wv * 64 + i] = q;
    __syncthreads();                                     // #3: o parts ready
    if (wv == 0) {
      float oi = o_part[i] + o_part[64 + i] + o_part[128 + i] + o_part[192 + i];
      og[rowbase + (size_t)t * DDIM + i] = oi;
    }
  }
}

// ---------------------------------------------------------------------------
// GroupNorm(16 groups of 64, eps=0.00064) + gate g, output bf16 for final GEMM
// one block per token row; 16 threads (x4 elems) per head
// ---------------------------------------------------------------------------
__global__ __launch_bounds__(256) void groupnorm_gate(
    const float* __restrict__ og, const float* __restrict__ g,
    const float* __restrict__ gnw, const float* __restrict__ gnb,
    unsigned short* __restrict__ ngb)
{
  const int bt = blockIdx.x;
  const int tid = threadIdx.x;
  const size_t base = (size_t)bt * DDIM + tid * 4;
  float4 v = *(const float4*)&og[base];
  float s  = v.x + v.y + v.z + v.w;
  float ss = v.x*v.x + v.y*v.y + v.z*v.z + v.w*v.w;
  s += __shfl_xor(s, 1); ss += __shfl_xor(ss, 1);
  s += __shfl_xor(s, 2); ss += __shfl_xor(ss, 2);
  s += __shfl_xor(s, 4); ss += __shfl_xor(ss, 4);
  s += __shfl_xor(s, 8); ss += __shfl_xor(ss, 8);
  float mean = s * (1.f / 64.f);
  float var  = ss * (1.f / 64.f) - mean * mean;
  float inv  = rsqrtf(var + 0.00064f);
  float4 w4 = *(const float4*)&gnw[tid * 4];
  float4 b4 = *(const float4*)&gnb[tid * 4];
  float4 g4 = *(const float4*)&g[base];
  us4 o;
  o.x = f2bf(((v.x - mean) * inv * w4.x + b4.x) * g4.x);
  o.y = f2bf(((v.y - mean) * inv * w4.y + b4.y) * g4.y);
  o.z = f2bf(((v.z - mean) * inv * w4.z + b4.z) * g4.z);
  o.w = f2bf(((v.w - mean) * inv * w4.w + b4.w) * g4.w);
  *(us4*)&ngb[base] = o;
}

// ---------------------------------------------------------------------------
extern "C" void kernel_launch(void* const* d_in, const int* in_sizes, int n_in,
                              void* d_out, int out_size, void* d_ws, size_t ws_size,
                              hipStream_t stream)
{
  (void)in_sizes; (void)n_in; (void)out_size; (void)ws_size;
  const float* x   = (const float*)d_in[0];
  const float* xr  = (const float*)d_in[1];
  const float* xw  = (const float*)d_in[2];
  const float* xk  = (const float*)d_in[3];
  const float* xv  = (const float*)d_in[4];
  const float* xa  = (const float*)d_in[5];
  const float* xb  = (const float*)d_in[6];
  const float* xg  = (const float*)d_in[7];
  const float* Wr  = (const float*)d_in[8];
  const float* Ww  = (const float*)d_in[9];
  const float* Wk  = (const float*)d_in[10];
  const float* Wv  = (const float*)d_in[11];
  const float* Wa  = (const float*)d_in[12];
  const float* Wb_ = (const float*)d_in[13];
  const float* Wg  = (const float*)d_in[14];
  const float* Wo  = (const float*)d_in[15];
  const float* bo  = (const float*)d_in[16];
  const float* gnw = (const float*)d_in[17];
  const float* gnb = (const float*)d_in[18];
  float* out = (float*)d_out;

  // workspace layout (bytes):
  //   Wb  bf16 [8][1024*1024]   @ 0          (16,777,216)
  //   xm  bf16 [7][4096*1024]   @ 16777216   (58,720,256)
  //   Y   f32  [7][4096*1024]   @ 75497472   (117,440,512)
  //   og  f32  [4096*1024]      @ 192937984  (16,777,216)
  //   ngb bf16 [4096*1024]      @ 209715200  (8,388,608)   → total 218,103,808
  char* ws = (char*)d_ws;
  unsigned short* Wbq = (unsigned short*)(ws);
  unsigned short* xm  = (unsigned short*)(ws + 16777216);
  float*          Y   = (float*)(ws + 75497472);
  float*          og  = (float*)(ws + 192937984);
  unsigned short* ngb = (unsigned short*)(ws + 209715200);

  const size_t MD = (size_t)MR * DDIM;      // 4194304
  const size_t WD = (size_t)DDIM * DDIM;    // 1048576

  cast_weights<<<8192, 256, 0, stream>>>(Wr, Ww, Wk, Wv, Wa, Wb_, Wg, Wo, Wbq);
  prep_mix<<<4096, 256, 0, stream>>>(x, xr, xw, xk, xv, xa, xb, xg, xm);

  // 7 fused projections + activations: Y = {r, exp(w), k, v, a_n, b_n, g}
  gemm_bt<<<dim3(DDIM / 128, MR / 128, 7), 256, 0, stream>>>(
      xm, Wbq, Y, MR, DDIM, DDIM, MD, WD, MD, -1, nullptr);

  rwkv_scan<<<64, 256, 0, stream>>>(Y, og);

  groupnorm_gate<<<MR, 256, 0, stream>>>(og, Y + 6 * MD, gnw, gnb, ngb);

  // out = ngb @ Wo^T + b_o
  gemm_bt<<<dim3(DDIM / 128, MR / 128, 1), 256, 0, stream>>>(
      ngb, Wbq + 7 * WD, out, MR, DDIM, DDIM, 0, 0, 0, 5, bo);
}

// Round 5
// 718.085 us; speedup vs baseline: 1.4648x; 1.4648x over previous
//
#include <hip/hip_runtime.h>
#include <cstdint>
#include <cstddef>

// Problem constants (fixed by the reference)
#define TT 1024          // seq len
#define BB 4             // batch
#define DDIM 1024        // d_model
#define HH 16            // heads
#define HKK 64           // head dim
#define MR (BB*TT)       // 4096 token rows

typedef __attribute__((__ext_vector_type__(8))) __bf16 bf16x8;
typedef __attribute__((__ext_vector_type__(4))) float f32x4;
typedef __attribute__((__ext_vector_type__(4))) unsigned short us4;
typedef __attribute__((__ext_vector_type__(4))) unsigned int ui4;

__device__ __forceinline__ unsigned short f2bf(float f) {
  unsigned int u = __builtin_bit_cast(unsigned int, f);
  u += 0x7fffu + ((u >> 16) & 1u);   // round-to-nearest-even
  return (unsigned short)(u >> 16);
}

// Direct global->LDS DMA, 16B per lane. LDS dest must be WAVE-UNIFORM base;
// HW writes lane l at base + l*16 (m104/m108). Casts go through uintptr_t
// (CK pattern) so they are legal integer->pointer reinterprets.
__device__ __forceinline__ void gload_lds16(const void* g, void* lds) {
  __builtin_amdgcn_global_load_lds(
      reinterpret_cast<const __attribute__((address_space(1))) unsigned int*>(
          reinterpret_cast<uintptr_t>(g)),
      reinterpret_cast<__attribute__((address_space(3))) unsigned int*>(
          reinterpret_cast<uintptr_t>(lds)),
      16, 0, 0);
}

// ---------------------------------------------------------------------------
// k0a: cast the 8 weight matrices (fp32 [1024][1024], row = out e, col = in d)
// to bf16 into Wb[8][1024*1024]
// ---------------------------------------------------------------------------
__global__ __launch_bounds__(256) void cast_weights(
    const float* __restrict__ W0, const float* __restrict__ W1,
    const float* __restrict__ W2, const float* __restrict__ W3,
    const float* __restrict__ W4, const float* __restrict__ W5,
    const float* __restrict__ W6, const float* __restrict__ W7,
    unsigned short* __restrict__ Wb)
{
  int idx = blockIdx.x * 256 + threadIdx.x;      // one float4 per thread
  int mid = idx >> 18;                            // 262144 float4s per matrix
  int off = idx & 262143;
  const float* W;
  switch (mid) {
    case 0: W = W0; break; case 1: W = W1; break;
    case 2: W = W2; break; case 3: W = W3; break;
    case 4: W = W4; break; case 5: W = W5; break;
    case 6: W = W6; break; default: W = W7; break;
  }
  float4 v = ((const float4*)W)[off];
  us4 o;
  o.x = f2bf(v.x); o.y = f2bf(v.y); o.z = f2bf(v.z); o.w = f2bf(v.w);
  *(us4*)&Wb[(size_t)mid * (1024u*1024u) + (size_t)off * 4] = o;
}

// ---------------------------------------------------------------------------
// k0b: build the 7 token-shift-mixed inputs in bf16:
//   xm[c][bt][d] = x[bt][d] + (prev[bt][d] - x[bt][d]) * mix_c[d]
// prev = x shifted by one token within each batch row (zero at t=0)
// ---------------------------------------------------------------------------
__global__ __launch_bounds__(256) void prep_mix(
    const float* __restrict__ x,
    const float* __restrict__ m0, const float* __restrict__ m1,
    const float* __restrict__ m2, const float* __restrict__ m3,
    const float* __restrict__ m4, const float* __restrict__ m5,
    const float* __restrict__ m6,
    unsigned short* __restrict__ xm)
{
  int idx = blockIdx.x * 256 + threadIdx.x;   // one float4 per thread; 1048576 total
  int dq  = idx & 255;                        // float4 index within the row
  int bt  = idx >> 8;
  int t   = bt & (TT - 1);
  const float4* x4 = (const float4*)x;
  float4 xv = x4[idx];
  float4 pv = make_float4(0.f, 0.f, 0.f, 0.f);
  if (t != 0) pv = x4[idx - 256];
  float4 dx = make_float4(pv.x - xv.x, pv.y - xv.y, pv.z - xv.z, pv.w - xv.w);
  const float* mixes[7] = {m0, m1, m2, m3, m4, m5, m6};
  const size_t MD = (size_t)MR * DDIM;
#pragma unroll
  for (int c = 0; c < 7; ++c) {
    float4 mc = ((const float4*)mixes[c])[dq];
    us4 o;
    o.x = f2bf(xv.x + dx.x * mc.x);
    o.y = f2bf(xv.y + dx.y * mc.y);
    o.z = f2bf(xv.z + dx.z * mc.z);
    o.w = f2bf(xv.w + dx.w * mc.w);
    *(us4*)&xm[c * MD + (size_t)idx * 4] = o;
  }
}

// ---------------------------------------------------------------------------
// GEMM: C[m][n] = sum_k A[m][k] * B[n][k]   (A,B bf16 row-major-K, C fp32)
// 128x128 tile, BK=32, 256 threads (4 waves 2x2), mfma_f32_16x16x32_bf16.
// Staging: global_load_lds width=16 (m97 structure, 2 barriers per K-step).
// Fused epilogue modes: 0 none | 1 sigmoid(-y) (exp(w) decay) | 2 tanh |
//                       3 sigmoid | 4 per-head l2norm (head==wave 64-col span) |
//                       5 +bias[col]
// mode_override<0: per-z table {r,w,k,v,a,b,g} = {0,1,2,0,4,4,3}
// ---------------------------------------------------------------------------
__global__ __launch_bounds__(256) void gemm_bt(
    const unsigned short* __restrict__ Aall,
    const unsigned short* __restrict__ Ball,
    float* __restrict__ Call,
    int M, int N, int K,
    size_t strideAz, size_t strideBz, size_t strideCz,
    int mode_override,
    const float* __restrict__ bias)
{
  (void)M;
  const int z = blockIdx.z;
  const unsigned short* A = Aall + (size_t)z * strideAz;
  const unsigned short* B = Ball + (size_t)z * strideBz;
  float* C = Call + (size_t)z * strideCz;
  int mode = mode_override;
  if (mode < 0) mode = (z == 1) ? 1 : (z == 2) ? 2 : (z == 4 || z == 5) ? 4 : (z == 6) ? 3 : 0;

  __shared__ unsigned short As[128 * 32];
  __shared__ unsigned short Bs[128 * 32];

  const int tid  = threadIdx.x;
  const int lane = tid & 63;
  const int wv   = tid >> 6;
  const int wr   = wv >> 1, wc = wv & 1;
  const int lr   = lane & 15, lh = lane >> 4;
  const int m0   = blockIdx.y * 128;
  const int n0   = blockIdx.x * 128;

  // staging geometry: thread tid sources 16B at row sr=(tid>>2), col 8*(tid&3);
  // its LDS slot is byte offset tid*16 == (wave base wv*1024) + lane*16
  const int sr = tid >> 2;
  const int sc = (tid & 3) * 8;
  char* asb = (char*)As + wv * 1024;   // wave-uniform LDS bases
  char* bsb = (char*)Bs + wv * 1024;

  f32x4 acc[4][4];
#pragma unroll
  for (int m = 0; m < 4; ++m)
#pragma unroll
    for (int n = 0; n < 4; ++n)
      acc[m][n] = (f32x4){0.f, 0.f, 0.f, 0.f};

  const unsigned short* a0p = A + (size_t)(m0 + sr) * K + sc;
  const unsigned short* a1p = A + (size_t)(m0 + 64 + sr) * K + sc;
  const unsigned short* b0p = B + (size_t)(n0 + sr) * K + sc;
  const unsigned short* b1p = B + (size_t)(n0 + 64 + sr) * K + sc;

  for (int k0 = 0; k0 < K; k0 += 32) {
    __syncthreads();                 // previous compute done reading LDS
    gload_lds16(a0p + k0, asb);
    gload_lds16(a1p + k0, asb + 4096);   // half1 starts at 64*32*2B
    gload_lds16(b0p + k0, bsb);
    gload_lds16(b1p + k0, bsb + 4096);
    __syncthreads();                 // drains vmcnt(0): tile ready
    bf16x8 af[4], bfr[4];
#pragma unroll
    for (int m = 0; m < 4; ++m)
      af[m] = *(const bf16x8*)&As[(wr * 64 + m * 16 + lr) * 32 + lh * 8];
#pragma unroll
    for (int n = 0; n < 4; ++n)
      bfr[n] = *(const bf16x8*)&Bs[(wc * 64 + n * 16 + lr) * 32 + lh * 8];
#pragma unroll
    for (int m = 0; m < 4; ++m)
#pragma unroll
      for (int n = 0; n < 4; ++n)
        acc[m][n] = __builtin_amdgcn_mfma_f32_16x16x32_bf16(af[m], bfr[n], acc[m][n], 0, 0, 0);
  }

  if (mode == 4) {
    // per-head l2norm: wave's 64-col span is exactly one head (n0,wc are 64-aligned)
#pragma unroll
    for (int m = 0; m < 4; ++m) {
#pragma unroll
      for (int r = 0; r < 4; ++r) {
        float ss = 0.f;
#pragma unroll
        for (int n = 0; n < 4; ++n) { float v = acc[m][n][r]; ss += v * v; }
        ss += __shfl_xor(ss, 1); ss += __shfl_xor(ss, 2);
        ss += __shfl_xor(ss, 4); ss += __shfl_xor(ss, 8);
        float scale = 1.f / fmaxf(sqrtf(ss), 1e-6f);
#pragma unroll
        for (int n = 0; n < 4; ++n) acc[m][n][r] *= scale;
      }
    }
  }

#pragma unroll
  for (int m = 0; m < 4; ++m) {
#pragma unroll
    for (int n = 0; n < 4; ++n) {
      int col = n0 + wc * 64 + n * 16 + lr;
#pragma unroll
      for (int r = 0; r < 4; ++r) {
        int row = m0 + wr * 64 + m * 16 + lh * 4 + r;
        float v = acc[m][n][r];
        if (mode == 1)      v = 1.f / (1.f + __expf(v));    // exp(w)=sigmoid(-y)
        else if (mode == 2) v = tanhf(v);
        else if (mode == 3) v = 1.f / (1.f + __expf(-v));
        else if (mode == 5) v += bias[col];
        C[(size_t)row * N + col] = v;
      }
    }
  }
}

// ---------------------------------------------------------------------------
// RWKV7 scan, barrier-free: rows of S are independent given the shared
// per-step vectors. 1024 blocks of 64 threads: block p -> (bh = p&63,
// rowgroup rg = p>>6). p%8 == bh%8 keeps all 16 rowgroups of a (b,h) on one
// XCD (L2 sharing). Wave owns 4 rows x 64 cols; lane l: row = l>>4,
// cols = (l&15)*4 + [0,4). State = 4 VGPRs/lane. The two 64-wide dots
// (S·a, S·r) = 4 FMA partials + 4-level shfl_xor butterfly over 16 lanes.
// 4-deep register prefetch (statically indexed) hides L2/L3 load latency.
// Tail prefetch over-reads <=4 rows past a plane end -> lands in the next
// Y plane (planes 0..6 exist), in-bounds.
// Y layout: [7][4096][1024] fp32 = r, decay(=exp(w)), k, v, a, b, g
// ---------------------------------------------------------------------------
__global__ __launch_bounds__(64) void rwkv_scan(
    const float* __restrict__ Y, float* __restrict__ og)
{
  const int p  = blockIdx.x;
  const int bh = p & 63;
  const int rg = p >> 6;
  const int b  = bh >> 4, h = bh & 15;
  const int l  = threadIdx.x;
  const int rl = l >> 4;            // row within group (0..3)
  const int cg = l & 15;            // column group
  const int c0 = cg * 4;
  const int r0 = rg * 4;

  const size_t MD = (size_t)MR * DDIM;
  const size_t base = (size_t)(b * TT) * DDIM + h * HKK;

  const float* Pr = Y + 0 * MD + base;
  const float* Pe = Y + 1 * MD + base;
  const float* Pk = Y + 2 * MD + base;
  const float* Pv = Y + 3 * MD + base;
  const float* Pa = Y + 4 * MD + base;
  const float* Pb = Y + 5 * MD + base;
  float* Po = og + base;

  float S0 = 0.f, S1 = 0.f, S2 = 0.f, S3 = 0.f;

  float4 rb[4], eb[4], kb[4], ab[4], bb[4];
  float  vb[4];

#pragma unroll
  for (int u = 0; u < 4; ++u) {
    size_t off = (size_t)u * DDIM;
    rb[u] = *(const float4*)(Pr + off + c0);
    eb[u] = *(const float4*)(Pe + off + c0);
    kb[u] = *(const float4*)(Pk + off + c0);
    ab[u] = *(const float4*)(Pa + off + c0);
    bb[u] = *(const float4*)(Pb + off + c0);
    vb[u] = Pv[off + r0 + rl];
  }

  for (int t = 0; t < TT; t += 4) {
#pragma unroll
    for (int u = 0; u < 4; ++u) {
      float4 a4 = ab[u], e4 = eb[u], k4 = kb[u], b4 = bb[u], r4 = rb[u];
      float  vi = vb[u];
      // issue prefetch for step t+u+4 into slot u (slot just consumed)
      size_t off = (size_t)(t + u + 4) * DDIM;
      rb[u] = *(const float4*)(Pr + off + c0);
      eb[u] = *(const float4*)(Pe + off + c0);
      kb[u] = *(const float4*)(Pk + off + c0);
      ab[u] = *(const float4*)(Pa + off + c0);
      bb[u] = *(const float4*)(Pb + off + c0);
      vb[u] = Pv[off + r0 + rl];
      // sa = S_row · a   (old state)
      float sp = S0 * a4.x + S1 * a4.y + S2 * a4.z + S3 * a4.w;
      sp += __shfl_xor(sp, 1);
      sp += __shfl_xor(sp, 2);
      sp += __shfl_xor(sp, 4);
      sp += __shfl_xor(sp, 8);
      // S = S*exp(w) + sa*b + v*k
      S0 = S0 * e4.x + sp * b4.x + vi * k4.x;
      S1 = S1 * e4.y + sp * b4.y + vi * k4.y;
      S2 = S2 * e4.z + sp * b4.z + vi * k4.z;
      S3 = S3 * e4.w + sp * b4.w + vi * k4.w;
      // o = S_row · r   (new state)
      float op = S0 * r4.x + S1 * r4.y + S2 * r4.z + S3 * r4.w;
      op += __shfl_xor(op, 1);
      op += __shfl_xor(op, 2);
      op += __shfl_xor(op, 4);
      op += __shfl_xor(op, 8);
      if (cg == 0) Po[(size_t)(t + u) * DDIM + r0 + rl] = op;
    }
  }
}

// ---------------------------------------------------------------------------
// GroupNorm(16 groups of 64, eps=0.00064) + gate g, output bf16 for final GEMM
// one block per token row; 16 threads (x4 elems) per head
// ---------------------------------------------------------------------------
__global__ __launch_bounds__(256) void groupnorm_gate(
    const float* __restrict__ og, const float* __restrict__ g,
    const float* __restrict__ gnw, const float* __restrict__ gnb,
    unsigned short* __restrict__ ngb)
{
  const int bt = blockIdx.x;
  const int tid = threadIdx.x;
  const size_t base = (size_t)bt * DDIM + tid * 4;
  float4 v = *(const float4*)&og[base];
  float s  = v.x + v.y + v.z + v.w;
  float ss = v.x*v.x + v.y*v.y + v.z*v.z + v.w*v.w;
  s += __shfl_xor(s, 1); ss += __shfl_xor(ss, 1);
  s += __shfl_xor(s, 2); ss += __shfl_xor(ss, 2);
  s += __shfl_xor(s, 4); ss += __shfl_xor(ss, 4);
  s += __shfl_xor(s, 8); ss += __shfl_xor(ss, 8);
  float mean = s * (1.f / 64.f);
  float var  = ss * (1.f / 64.f) - mean * mean;
  float inv  = rsqrtf(var + 0.00064f);
  float4 w4 = *(const float4*)&gnw[tid * 4];
  float4 b4 = *(const float4*)&gnb[tid * 4];
  float4 g4 = *(const float4*)&g[base];
  us4 o;
  o.x = f2bf(((v.x - mean) * inv * w4.x + b4.x) * g4.x);
  o.y = f2bf(((v.y - mean) * inv * w4.y + b4.y) * g4.y);
  o.z = f2bf(((v.z - mean) * inv * w4.z + b4.z) * g4.z);
  o.w = f2bf(((v.w - mean) * inv * w4.w + b4.w) * g4.w);
  *(us4*)&ngb[base] = o;
}

// ---------------------------------------------------------------------------
extern "C" void kernel_launch(void* const* d_in, const int* in_sizes, int n_in,
                              void* d_out, int out_size, void* d_ws, size_t ws_size,
                              hipStream_t stream)
{
  (void)in_sizes; (void)n_in; (void)out_size; (void)ws_size;
  const float* x   = (const float*)d_in[0];
  const float* xr  = (const float*)d_in[1];
  const float* xw  = (const float*)d_in[2];
  const float* xk  = (const float*)d_in[3];
  const float* xv  = (const float*)d_in[4];
  const float* xa  = (const float*)d_in[5];
  const float* xb  = (const float*)d_in[6];
  const float* xg  = (const float*)d_in[7];
  const float* Wr  = (const float*)d_in[8];
  const float* Ww  = (const float*)d_in[9];
  const float* Wk  = (const float*)d_in[10];
  const float* Wv  = (const float*)d_in[11];
  const float* Wa  = (const float*)d_in[12];
  const float* Wb_ = (const float*)d_in[13];
  const float* Wg  = (const float*)d_in[14];
  const float* Wo  = (const float*)d_in[15];
  const float* bo  = (const float*)d_in[16];
  const float* gnw = (const float*)d_in[17];
  const float* gnb = (const float*)d_in[18];
  float* out = (float*)d_out;

  // workspace layout (bytes):
  //   Wb  bf16 [8][1024*1024]   @ 0          (16,777,216)
  //   xm  bf16 [7][4096*1024]   @ 16777216   (58,720,256)
  //   Y   f32  [7][4096*1024]   @ 75497472   (117,440,512)
  //   og  f32  [4096*1024]      @ 192937984  (16,777,216)
  //   ngb bf16 [4096*1024]      @ 209715200  (8,388,608)   → total 218,103,808
  char* ws = (char*)d_ws;
  unsigned short* Wbq = (unsigned short*)(ws);
  unsigned short* xm  = (unsigned short*)(ws + 16777216);
  float*          Y   = (float*)(ws + 75497472);
  float*          og  = (float*)(ws + 192937984);
  unsigned short* ngb = (unsigned short*)(ws + 209715200);

  const size_t MD = (size_t)MR * DDIM;      // 4194304
  const size_t WD = (size_t)DDIM * DDIM;    // 1048576

  cast_weights<<<8192, 256, 0, stream>>>(Wr, Ww, Wk, Wv, Wa, Wb_, Wg, Wo, Wbq);
  prep_mix<<<4096, 256, 0, stream>>>(x, xr, xw, xk, xv, xa, xb, xg, xm);

  // 7 fused projections + activations: Y = {r, exp(w), k, v, a_n, b_n, g}
  gemm_bt<<<dim3(DDIM / 128, MR / 128, 7), 256, 0, stream>>>(
      xm, Wbq, Y, MR, DDIM, DDIM, MD, WD, MD, -1, nullptr);

  rwkv_scan<<<1024, 64, 0, stream>>>(Y, og);

  groupnorm_gate<<<MR, 256, 0, stream>>>(og, Y + 6 * MD, gnw, gnb, ngb);

  // out = ngb @ Wo^T + b_o
  gemm_bt<<<dim3(DDIM / 128, MR / 128, 1), 256, 0, stream>>>(
      ngb, Wbq + 7 * WD, out, MR, DDIM, DDIM, 0, 0, 0, 5, bo);
}

// Round 9
// 596.401 us; speedup vs baseline: 1.7636x; 1.2040x over previous
//
#include <hip/hip_runtime.h>
#include <cstdint>
#include <cstddef>

// Problem constants (fixed by the reference)
#define TT 1024          // seq len
#define BB 4             // batch
#define DDIM 1024        // d_model
#define HH 16            // heads
#define HKK 64           // head dim
#define MR (BB*TT)       // 4096 token rows

typedef __attribute__((__ext_vector_type__(8))) __bf16 bf16x8;
typedef __attribute__((__ext_vector_type__(4))) float f32x4;
typedef __attribute__((__ext_vector_type__(4))) unsigned short us4;
typedef __attribute__((__ext_vector_type__(4))) unsigned int ui4;

__device__ __forceinline__ unsigned short f2bf(float f) {
  unsigned int u = __builtin_bit_cast(unsigned int, f);
  u += 0x7fffu + ((u >> 16) & 1u);   // round-to-nearest-even
  return (unsigned short)(u >> 16);
}

// 16-lane sum via DPP row_ror rotate-add chain (VALU latency, no LDS pipe).
// row_ror:N ctrl = 0x120|N; rows of 16 lanes == our column groups (aligned).
// After ror 1,2,4,8 adds, every lane of the 16-group holds the full sum.
#define ROR_ADD(x, N)                                                        \
  x += __builtin_bit_cast(float, __builtin_amdgcn_update_dpp(                \
      0, __builtin_bit_cast(int, x), 0x120 | (N), 0xF, 0xF, 0))

// Direct global->LDS DMA, 16B per lane. LDS dest must be WAVE-UNIFORM base;
// HW writes lane l at base + l*16 (m104/m108). Casts go through uintptr_t
// (CK pattern) so they are legal integer->pointer reinterprets.
__device__ __forceinline__ void gload_lds16(const void* g, void* lds) {
  __builtin_amdgcn_global_load_lds(
      reinterpret_cast<const __attribute__((address_space(1))) unsigned int*>(
          reinterpret_cast<uintptr_t>(g)),
      reinterpret_cast<__attribute__((address_space(3))) unsigned int*>(
          reinterpret_cast<uintptr_t>(lds)),
      16, 0, 0);
}

// ---------------------------------------------------------------------------
// k0a: cast the 8 weight matrices (fp32 [1024][1024], row = out e, col = in d)
// to bf16 into Wb[8][1024*1024]
// ---------------------------------------------------------------------------
__global__ __launch_bounds__(256) void cast_weights(
    const float* __restrict__ W0, const float* __restrict__ W1,
    const float* __restrict__ W2, const float* __restrict__ W3,
    const float* __restrict__ W4, const float* __restrict__ W5,
    const float* __restrict__ W6, const float* __restrict__ W7,
    unsigned short* __restrict__ Wb)
{
  int idx = blockIdx.x * 256 + threadIdx.x;      // one float4 per thread
  int mid = idx >> 18;                            // 262144 float4s per matrix
  int off = idx & 262143;
  const float* W;
  switch (mid) {
    case 0: W = W0; break; case 1: W = W1; break;
    case 2: W = W2; break; case 3: W = W3; break;
    case 4: W = W4; break; case 5: W = W5; break;
    case 6: W = W6; break; default: W = W7; break;
  }
  float4 v = ((const float4*)W)[off];
  us4 o;
  o.x = f2bf(v.x); o.y = f2bf(v.y); o.z = f2bf(v.z); o.w = f2bf(v.w);
  *(us4*)&Wb[(size_t)mid * (1024u*1024u) + (size_t)off * 4] = o;
}

// ---------------------------------------------------------------------------
// k0b: build the 7 token-shift-mixed inputs in bf16:
//   xm[c][bt][d] = x[bt][d] + (prev[bt][d] - x[bt][d]) * mix_c[d]
// prev = x shifted by one token within each batch row (zero at t=0)
// ---------------------------------------------------------------------------
__global__ __launch_bounds__(256) void prep_mix(
    const float* __restrict__ x,
    const float* __restrict__ m0, const float* __restrict__ m1,
    const float* __restrict__ m2, const float* __restrict__ m3,
    const float* __restrict__ m4, const float* __restrict__ m5,
    const float* __restrict__ m6,
    unsigned short* __restrict__ xm)
{
  int idx = blockIdx.x * 256 + threadIdx.x;   // one float4 per thread; 1048576 total
  int dq  = idx & 255;                        // float4 index within the row
  int bt  = idx >> 8;
  int t   = bt & (TT - 1);
  const float4* x4 = (const float4*)x;
  float4 xv = x4[idx];
  float4 pv = make_float4(0.f, 0.f, 0.f, 0.f);
  if (t != 0) pv = x4[idx - 256];
  float4 dx = make_float4(pv.x - xv.x, pv.y - xv.y, pv.z - xv.z, pv.w - xv.w);
  const float* mixes[7] = {m0, m1, m2, m3, m4, m5, m6};
  const size_t MD = (size_t)MR * DDIM;
#pragma unroll
  for (int c = 0; c < 7; ++c) {
    float4 mc = ((const float4*)mixes[c])[dq];
    us4 o;
    o.x = f2bf(xv.x + dx.x * mc.x);
    o.y = f2bf(xv.y + dx.y * mc.y);
    o.z = f2bf(xv.z + dx.z * mc.z);
    o.w = f2bf(xv.w + dx.w * mc.w);
    *(us4*)&xm[c * MD + (size_t)idx * 4] = o;
  }
}

// ---------------------------------------------------------------------------
// GEMM: C[m][n] = sum_k A[m][k] * B[n][k]   (A,B bf16 row-major-K, C fp32)
// 128x128 tile, BK=32, 256 threads (4 waves 2x2), mfma_f32_16x16x32_bf16.
// Staging: global_load_lds width=16 (m97 structure, 2 barriers per K-step).
// Fused epilogue modes: 0 none | 1 sigmoid(-y) (exp(w) decay) | 2 tanh |
//                       3 sigmoid | 4 per-head l2norm (head==wave 64-col span) |
//                       5 +bias[col]
// mode_override<0: per-z table {r,w,k,v,a,b,g} = {0,1,2,0,4,4,3}
// ---------------------------------------------------------------------------
__global__ __launch_bounds__(256) void gemm_bt(
    const unsigned short* __restrict__ Aall,
    const unsigned short* __restrict__ Ball,
    float* __restrict__ Call,
    int M, int N, int K,
    size_t strideAz, size_t strideBz, size_t strideCz,
    int mode_override,
    const float* __restrict__ bias)
{
  (void)M;
  const int z = blockIdx.z;
  const unsigned short* A = Aall + (size_t)z * strideAz;
  const unsigned short* B = Ball + (size_t)z * strideBz;
  float* C = Call + (size_t)z * strideCz;
  int mode = mode_override;
  if (mode < 0) mode = (z == 1) ? 1 : (z == 2) ? 2 : (z == 4 || z == 5) ? 4 : (z == 6) ? 3 : 0;

  __shared__ unsigned short As[128 * 32];
  __shared__ unsigned short Bs[128 * 32];

  const int tid  = threadIdx.x;
  const int lane = tid & 63;
  const int wv   = tid >> 6;
  const int wr   = wv >> 1, wc = wv & 1;
  const int lr   = lane & 15, lh = lane >> 4;
  const int m0   = blockIdx.y * 128;
  const int n0   = blockIdx.x * 128;

  // staging geometry: thread tid sources 16B at row sr=(tid>>2), col 8*(tid&3);
  // its LDS slot is byte offset tid*16 == (wave base wv*1024) + lane*16
  const int sr = tid >> 2;
  const int sc = (tid & 3) * 8;
  char* asb = (char*)As + wv * 1024;   // wave-uniform LDS bases
  char* bsb = (char*)Bs + wv * 1024;

  f32x4 acc[4][4];
#pragma unroll
  for (int m = 0; m < 4; ++m)
#pragma unroll
    for (int n = 0; n < 4; ++n)
      acc[m][n] = (f32x4){0.f, 0.f, 0.f, 0.f};

  const unsigned short* a0p = A + (size_t)(m0 + sr) * K + sc;
  const unsigned short* a1p = A + (size_t)(m0 + 64 + sr) * K + sc;
  const unsigned short* b0p = B + (size_t)(n0 + sr) * K + sc;
  const unsigned short* b1p = B + (size_t)(n0 + 64 + sr) * K + sc;

  for (int k0 = 0; k0 < K; k0 += 32) {
    __syncthreads();                 // previous compute done reading LDS
    gload_lds16(a0p + k0, asb);
    gload_lds16(a1p + k0, asb + 4096);   // half1 starts at 64*32*2B
    gload_lds16(b0p + k0, bsb);
    gload_lds16(b1p + k0, bsb + 4096);
    __syncthreads();                 // drains vmcnt(0): tile ready
    bf16x8 af[4], bfr[4];
#pragma unroll
    for (int m = 0; m < 4; ++m)
      af[m] = *(const bf16x8*)&As[(wr * 64 + m * 16 + lr) * 32 + lh * 8];
#pragma unroll
    for (int n = 0; n < 4; ++n)
      bfr[n] = *(const bf16x8*)&Bs[(wc * 64 + n * 16 + lr) * 32 + lh * 8];
#pragma unroll
    for (int m = 0; m < 4; ++m)
#pragma unroll
      for (int n = 0; n < 4; ++n)
        acc[m][n] = __builtin_amdgcn_mfma_f32_16x16x32_bf16(af[m], bfr[n], acc[m][n], 0, 0, 0);
  }

  if (mode == 4) {
    // per-head l2norm: wave's 64-col span is exactly one head (n0,wc are 64-aligned)
#pragma unroll
    for (int m = 0; m < 4; ++m) {
#pragma unroll
      for (int r = 0; r < 4; ++r) {
        float ss = 0.f;
#pragma unroll
        for (int n = 0; n < 4; ++n) { float v = acc[m][n][r]; ss += v * v; }
        ss += __shfl_xor(ss, 1); ss += __shfl_xor(ss, 2);
        ss += __shfl_xor(ss, 4); ss += __shfl_xor(ss, 8);
        float scale = 1.f / fmaxf(sqrtf(ss), 1e-6f);
#pragma unroll
        for (int n = 0; n < 4; ++n) acc[m][n][r] *= scale;
      }
    }
  }

#pragma unroll
  for (int m = 0; m < 4; ++m) {
#pragma unroll
    for (int n = 0; n < 4; ++n) {
      int col = n0 + wc * 64 + n * 16 + lr;
#pragma unroll
      for (int r = 0; r < 4; ++r) {
        int row = m0 + wr * 64 + m * 16 + lh * 4 + r;
        float v = acc[m][n][r];
        if (mode == 1)      v = 1.f / (1.f + __expf(v));    // exp(w)=sigmoid(-y)
        else if (mode == 2) v = tanhf(v);
        else if (mode == 3) v = 1.f / (1.f + __expf(-v));
        else if (mode == 5) v += bias[col];
        C[(size_t)row * N + col] = v;
      }
    }
  }
}

// ---------------------------------------------------------------------------
// RWKV7 scan, barrier-free: 1024 blocks of 64 threads: block p -> (bh = p&63,
// rowgroup rg = p>>6). Wave owns 4 rows x 64 cols; lane l: row = l>>4,
// cols = (l&15)*4 + [0,4). State = 4 VGPRs/lane. The two 64-wide dots
// (S·a, S·r) reduce over the 16-lane colgroup via DPP row_ror add chains
// (VALU latency; hip __shfl_xor lowers to ds_bpermute = LDS-pipe latency,
// which was the round-5 stall: 8 serial ds ops/step x ~50cyc).
// __launch_bounds__(64,1): blocks (1024 = 1/SIMD) limit occupancy, not VGPRs,
// so let the allocator keep the full 4-deep prefetch (~84 data VGPRs) live.
// Tail prefetch over-reads <=4 rows past a plane end -> lands in the next
// Y plane (planes 0..6 exist), in-bounds.
// Y layout: [7][4096][1024] fp32 = r, decay(=exp(w)), k, v, a, b, g
// ---------------------------------------------------------------------------
__global__ __launch_bounds__(64, 1) void rwkv_scan(
    const float* __restrict__ Y, float* __restrict__ og)
{
  const int p  = blockIdx.x;
  const int bh = p & 63;
  const int rg = p >> 6;
  const int b  = bh >> 4, h = bh & 15;
  const int l  = threadIdx.x;
  const int rl = l >> 4;            // row within group (0..3)
  const int cg = l & 15;            // column group
  const int c0 = cg * 4;
  const int r0 = rg * 4;

  const size_t MD = (size_t)MR * DDIM;
  const size_t base = (size_t)(b * TT) * DDIM + h * HKK;

  const float* Pr = Y + 0 * MD + base;
  const float* Pe = Y + 1 * MD + base;
  const float* Pk = Y + 2 * MD + base;
  const float* Pv = Y + 3 * MD + base;
  const float* Pa = Y + 4 * MD + base;
  const float* Pb = Y + 5 * MD + base;
  float* Po = og + base;

  float S0 = 0.f, S1 = 0.f, S2 = 0.f, S3 = 0.f;

  float4 rb[4], eb[4], kb[4], ab[4], bb[4];
  float  vb[4];

#pragma unroll
  for (int u = 0; u < 4; ++u) {
    size_t off = (size_t)u * DDIM;
    rb[u] = *(const float4*)(Pr + off + c0);
    eb[u] = *(const float4*)(Pe + off + c0);
    kb[u] = *(const float4*)(Pk + off + c0);
    ab[u] = *(const float4*)(Pa + off + c0);
    bb[u] = *(const float4*)(Pb + off + c0);
    vb[u] = Pv[off + r0 + rl];
  }

  for (int t = 0; t < TT; t += 4) {
#pragma unroll
    for (int u = 0; u < 4; ++u) {
      float4 a4 = ab[u], e4 = eb[u], k4 = kb[u], b4 = bb[u], r4 = rb[u];
      float  vi = vb[u];
      // issue prefetch for step t+u+4 into slot u (slot just consumed)
      size_t off = (size_t)(t + u + 4) * DDIM;
      rb[u] = *(const float4*)(Pr + off + c0);
      eb[u] = *(const float4*)(Pe + off + c0);
      kb[u] = *(const float4*)(Pk + off + c0);
      ab[u] = *(const float4*)(Pa + off + c0);
      bb[u] = *(const float4*)(Pb + off + c0);
      vb[u] = Pv[off + r0 + rl];
      // sa = S_row · a   (old state), 16-lane DPP rotate-add reduce
      float sp = S0 * a4.x + S1 * a4.y + S2 * a4.z + S3 * a4.w;
      ROR_ADD(sp, 1); ROR_ADD(sp, 2); ROR_ADD(sp, 4); ROR_ADD(sp, 8);
      // S = S*exp(w) + sa*b + v*k
      S0 = S0 * e4.x + sp * b4.x + vi * k4.x;
      S1 = S1 * e4.y + sp * b4.y + vi * k4.y;
      S2 = S2 * e4.z + sp * b4.z + vi * k4.z;
      S3 = S3 * e4.w + sp * b4.w + vi * k4.w;
      // o = S_row · r   (new state)
      float op = S0 * r4.x + S1 * r4.y + S2 * r4.z + S3 * r4.w;
      ROR_ADD(op, 1); ROR_ADD(op, 2); ROR_ADD(op, 4); ROR_ADD(op, 8);
      if (cg == 0) Po[(size_t)(t + u) * DDIM + r0 + rl] = op;
    }
  }
}

// ---------------------------------------------------------------------------
// GroupNorm(16 groups of 64, eps=0.00064) + gate g, output bf16 for final GEMM
// one block per token row; 16 threads (x4 elems) per head
// ---------------------------------------------------------------------------
__global__ __launch_bounds__(256) void groupnorm_gate(
    const float* __restrict__ og, const float* __restrict__ g,
    const float* __restrict__ gnw, const float* __restrict__ gnb,
    unsigned short* __restrict__ ngb)
{
  const int bt = blockIdx.x;
  const int tid = threadIdx.x;
  const size_t base = (size_t)bt * DDIM + tid * 4;
  float4 v = *(const float4*)&og[base];
  float s  = v.x + v.y + v.z + v.w;
  float ss = v.x*v.x + v.y*v.y + v.z*v.z + v.w*v.w;
  s += __shfl_xor(s, 1); ss += __shfl_xor(ss, 1);
  s += __shfl_xor(s, 2); ss += __shfl_xor(ss, 2);
  s += __shfl_xor(s, 4); ss += __shfl_xor(ss, 4);
  s += __shfl_xor(s, 8); ss += __shfl_xor(ss, 8);
  float mean = s * (1.f / 64.f);
  float var  = ss * (1.f / 64.f) - mean * mean;
  float inv  = rsqrtf(var + 0.00064f);
  float4 w4 = *(const float4*)&gnw[tid * 4];
  float4 b4 = *(const float4*)&gnb[tid * 4];
  float4 g4 = *(const float4*)&g[base];
  us4 o;
  o.x = f2bf(((v.x - mean) * inv * w4.x + b4.x) * g4.x);
  o.y = f2bf(((v.y - mean) * inv * w4.y + b4.y) * g4.y);
  o.z = f2bf(((v.z - mean) * inv * w4.z + b4.z) * g4.z);
  o.w = f2bf(((v.w - mean) * inv * w4.w + b4.w) * g4.w);
  *(us4*)&ngb[base] = o;
}

// ---------------------------------------------------------------------------
extern "C" void kernel_launch(void* const* d_in, const int* in_sizes, int n_in,
                              void* d_out, int out_size, void* d_ws, size_t ws_size,
                              hipStream_t stream)
{
  (void)in_sizes; (void)n_in; (void)out_size; (void)ws_size;
  const float* x   = (const float*)d_in[0];
  const float* xr  = (const float*)d_in[1];
  const float* xw  = (const float*)d_in[2];
  const float* xk  = (const float*)d_in[3];
  const float* xv  = (const float*)d_in[4];
  const float* xa  = (const float*)d_in[5];
  const float* xb  = (const float*)d_in[6];
  const float* xg  = (const float*)d_in[7];
  const float* Wr  = (const float*)d_in[8];
  const float* Ww  = (const float*)d_in[9];
  const float* Wk  = (const float*)d_in[10];
  const float* Wv  = (const float*)d_in[11];
  const float* Wa  = (const float*)d_in[12];
  const float* Wb_ = (const float*)d_in[13];
  const float* Wg  = (const float*)d_in[14];
  const float* Wo  = (const float*)d_in[15];
  const float* bo  = (const float*)d_in[16];
  const float* gnw = (const float*)d_in[17];
  const float* gnb = (const float*)d_in[18];
  float* out = (float*)d_out;

  // workspace layout (bytes):
  //   Wb  bf16 [8][1024*1024]   @ 0          (16,777,216)
  //   xm  bf16 [7][4096*1024]   @ 16777216   (58,720,256)
  //   Y   f32  [7][4096*1024]   @ 75497472   (117,440,512)
  //   og  f32  [4096*1024]      @ 192937984  (16,777,216)
  //   ngb bf16 [4096*1024]      @ 209715200  (8,388,608)   → total 218,103,808
  char* ws = (char*)d_ws;
  unsigned short* Wbq = (unsigned short*)(ws);
  unsigned short* xm  = (unsigned short*)(ws + 16777216);
  float*          Y   = (float*)(ws + 75497472);
  float*          og  = (float*)(ws + 192937984);
  unsigned short* ngb = (unsigned short*)(ws + 209715200);

  const size_t MD = (size_t)MR * DDIM;      // 4194304
  const size_t WD = (size_t)DDIM * DDIM;    // 1048576

  cast_weights<<<8192, 256, 0, stream>>>(Wr, Ww, Wk, Wv, Wa, Wb_, Wg, Wo, Wbq);
  prep_mix<<<4096, 256, 0, stream>>>(x, xr, xw, xk, xv, xa, xb, xg, xm);

  // 7 fused projections + activations: Y = {r, exp(w), k, v, a_n, b_n, g}
  gemm_bt<<<dim3(DDIM / 128, MR / 128, 7), 256, 0, stream>>>(
      xm, Wbq, Y, MR, DDIM, DDIM, MD, WD, MD, -1, nullptr);

  rwkv_scan<<<1024, 64, 0, stream>>>(Y, og);

  groupnorm_gate<<<MR, 256, 0, stream>>>(og, Y + 6 * MD, gnw, gnb, ngb);

  // out = ngb @ Wo^T + b_o
  gemm_bt<<<dim3(DDIM / 128, MR / 128, 1), 256, 0, stream>>>(
      ngb, Wbq + 7 * WD, out, MR, DDIM, DDIM, 0, 0, 0, 5, bo);
}